// Round 1
// baseline (303.253 us; speedup 1.0000x reference)
//
#include <hip/hip_runtime.h>
#include <math.h>

// ---------------------------------------------------------------------------
// YOLOv5-style loss, 3 layers, fp32.
// Inputs per layer i (base = 8*i):
//   [8i]   pred  : float [16, 255, g, g]
//   [8i+1] b     : int   [n]
//   [8i+2] a     : int   [n]
//   [8i+3] gj    : int   [n]   (row / h index)
//   [8i+4] gi    : int   [n]   (col / w index)
//   [8i+5] tbox  : float [n,4]
//   [8i+6] tcls  : int   [n]
//   [8i+7] anc   : float [n,2]
// Output: loss scalar (float[1]).
//
// Decomposition: bce(x,t) = bce(x,0) - x*t.
//   cls = sum_{n,80} bce(x,0) - sum_n x[tcls]
//   obj = sum_cells bce(x,0) - sum_{winner cells} x * clip(iou,0)
// Duplicate scatter indices: numpy .at[].set() is last-write-wins ->
// per-cell atomicMax of (entry_idx+1) selects the last occurrence.
// ---------------------------------------------------------------------------

#define EPS 1e-7f
#define BS 16
#define NA 3
#define NC 80

struct Layer {
    const float* pred;
    const int*   b;
    const int*   a;
    const int*   gj;
    const int*   gi;
    const int*   tcls;
    const float* tbox;
    const float* anc;
    unsigned int* winner;   // [48*g*g] cells, 0 = empty else entry_idx+1
    float*        iou;      // [n] CIoU per entry
    int g;
    int n;
};

struct Args {
    Layer L[3];
    int cum0;   // blocks of layer 0
    int cum1;   // blocks of layers 0+1
};

__device__ __forceinline__ int pick_layer(const Args& A, int& lb) {
    int bid = blockIdx.x;
    if (bid < A.cum0) { lb = bid; return 0; }
    if (bid < A.cum1) { lb = bid - A.cum0; return 1; }
    lb = bid - A.cum1; return 2;
}

__device__ __forceinline__ float block_reduce256(float v) {
    #pragma unroll
    for (int o = 32; o > 0; o >>= 1) v += __shfl_down(v, o, 64);
    __shared__ float sm[4];
    int lane = threadIdx.x & 63;
    int wid  = threadIdx.x >> 6;
    if (lane == 0) sm[wid] = v;
    __syncthreads();
    if (threadIdx.x == 0) v = sm[0] + sm[1] + sm[2] + sm[3];
    return v;
}

__device__ __forceinline__ float bce0(float x) {
    // bce_with_logits(x, 0) = max(x,0) + log1p(exp(-|x|))
    return fmaxf(x, 0.f) + log1pf(expf(-fabsf(x)));
}

// --- kernel 1: per-entry CIoU, box loss, scatter winner ---------------------
__global__ void entry_kernel(Args A, float* acc) {
    int lb; int layer = pick_layer(A, lb);
    const Layer L = A.L[layer];
    int j = lb * 256 + (int)threadIdx.x;
    float contrib = 0.f;
    if (j < L.n) {
        int b  = L.b[j],  a  = L.a[j];
        int gy = L.gj[j], gx = L.gi[j];
        int g = L.g, gg = g * g;
        const float* base = L.pred + ((size_t)(b * 255 + a * 85) * gg + (size_t)gy * g + gx);
        float px = base[0];
        float py = base[gg];
        float pw = base[2 * (size_t)gg];
        float ph = base[3 * (size_t)gg];
        // decode
        float cx = 2.f / (1.f + expf(-px)) - 0.5f;
        float cy = 2.f / (1.f + expf(-py)) - 0.5f;
        float sw = 2.f / (1.f + expf(-pw));
        float sh = 2.f / (1.f + expf(-ph));
        float bw = sw * sw * L.anc[2 * j];
        float bh = sh * sh * L.anc[2 * j + 1];
        // target box in feature-map units, center relative to cell
        float fg = (float)g;
        float tx = L.tbox[4 * j + 0] * fg - (float)gx;
        float ty = L.tbox[4 * j + 1] * fg - (float)gy;
        float tw = L.tbox[4 * j + 2] * fg;
        float th = L.tbox[4 * j + 3] * fg;
        // CIoU (mirrors ciou_xywh)
        float b1x1 = cx - bw * 0.5f, b1x2 = cx + bw * 0.5f;
        float b1y1 = cy - bh * 0.5f, b1y2 = cy + bh * 0.5f;
        float b2x1 = tx - tw * 0.5f, b2x2 = tx + tw * 0.5f;
        float b2y1 = ty - th * 0.5f, b2y2 = ty + th * 0.5f;
        float iw = fminf(b1x2, b2x2) - fmaxf(b1x1, b2x1);
        float ih = fminf(b1y2, b2y2) - fmaxf(b1y1, b2y1);
        float inter = fmaxf(iw, 0.f) * fmaxf(ih, 0.f);
        float w1 = b1x2 - b1x1, h1 = b1y2 - b1y1 + EPS;
        float w2 = b2x2 - b2x1, h2 = b2y2 - b2y1 + EPS;
        float uni = w1 * h1 + w2 * h2 - inter + EPS;
        float iou = inter / uni;
        float cw  = fmaxf(b1x2, b2x2) - fminf(b1x1, b2x1);
        float chh = fmaxf(b1y2, b2y2) - fminf(b1y1, b2y1);
        float c2  = cw * cw + chh * chh + EPS;
        float dx = b2x1 + b2x2 - b1x1 - b1x2;
        float dy = b2y1 + b2y2 - b1y1 - b1y2;
        float rho2 = (dx * dx + dy * dy) * 0.25f;
        float dv = atanf(w2 / h2) - atanf(w1 / h1);
        float v = (4.f / (float)(M_PI * M_PI)) * dv * dv;
        float alpha = v / (v - iou + (1.f + EPS));
        float ciou = iou - (rho2 / c2 + v * alpha);
        L.iou[j] = ciou;
        int cell = ((b * NA + a) * g + gy) * g + gx;
        atomicMax(&L.winner[cell], (unsigned int)(j + 1));
        contrib = 1.f - ciou;
    }
    float s = block_reduce256(contrib);
    if (threadIdx.x == 0) atomicAdd(&acc[0 + layer], s);
}

// --- kernel 2: per-(entry, class) BCE --------------------------------------
__global__ void cls_kernel(Args A, float* acc) {
    int lb; int layer = pick_layer(A, lb);
    const Layer L = A.L[layer];
    int p = lb * 256 + (int)threadIdx.x;
    int j = p / NC;
    int c = p - j * NC;
    float e = 0.f;
    if (j < L.n) {
        int b  = L.b[j],  a  = L.a[j];
        int gy = L.gj[j], gx = L.gi[j];
        int g = L.g, gg = g * g;
        size_t base = (size_t)(b * 255 + a * 85) * gg + (size_t)gy * g + gx;
        float x = L.pred[base + (size_t)(5 + c) * gg];
        e = bce0(x);
        if (c == L.tcls[j]) e -= x;   // bce(x,1) = bce(x,0) - x
    }
    float s = block_reduce256(e);
    if (threadIdx.x == 0) atomicAdd(&acc[6 + layer], s);
}

// --- kernel 3: per-cell objectness BCE + scatter correction ----------------
__global__ void obj_kernel(Args A, float* acc) {
    int lb; int layer = pick_layer(A, lb);
    const Layer L = A.L[layer];
    int cell = lb * 256 + (int)threadIdx.x;
    int g = L.g, gg = g * g;
    int cells = BS * NA * gg;
    float e = 0.f;
    if (cell < cells) {
        int q  = cell / gg;          // b*NA + a
        int yx = cell - q * gg;
        float x = L.pred[(size_t)(85 * q + 4) * gg + yx];
        e = bce0(x);
        unsigned int w = L.winner[cell];
        if (w) e -= x * fmaxf(L.iou[w - 1], 0.f);   // bce(x,t) = bce(x,0) - x*t
    }
    float s = block_reduce256(e);
    if (threadIdx.x == 0) atomicAdd(&acc[3 + layer], s);
}

// --- kernel 4: combine ------------------------------------------------------
__global__ void final_kernel(const float* acc, float* out,
                             int n0, int n1, int n2,
                             int c0, int c1, int c2) {
    float box_l = acc[0] / (float)n0 + acc[1] / (float)n1 + acc[2] / (float)n2;
    float obj_l = 0.4f * acc[3] / (float)c0
                + 1.0f * acc[4] / (float)c1
                + 4.0f * acc[5] / (float)c2;
    float cls_l = acc[6] / ((float)n0 * NC)
                + acc[7] / ((float)n1 * NC)
                + acc[8] / ((float)n2 * NC);
    out[0] = 0.05f * box_l + 1.0f * obj_l + 0.5f * cls_l;
}

extern "C" void kernel_launch(void* const* d_in, const int* in_sizes, int n_in,
                              void* d_out, int out_size, void* d_ws, size_t ws_size,
                              hipStream_t stream) {
    (void)n_in; (void)out_size;
    char* ws = (char*)d_ws;

    Args A;
    int n[3], g[3], cells[3];
    size_t off = 64;                       // bytes 0..63: 9 float accumulators
    size_t winner_off[3], iou_off[3];

    for (int i = 0; i < 3; ++i) {
        n[i] = in_sizes[8 * i + 1];
        int gg = in_sizes[8 * i] / (BS * 255);
        int gv = (int)(sqrt((double)gg) + 0.5);
        g[i] = gv;
        cells[i] = BS * NA * gv * gv;
        winner_off[i] = off; off += (size_t)cells[i] * 4;
    }
    size_t zero_bytes = off;               // accumulators + winner arrays
    for (int i = 0; i < 3; ++i) { iou_off[i] = off; off += (size_t)n[i] * 4; }
    (void)ws_size;  // off <= ~1.7 MB, assumed within workspace

    for (int i = 0; i < 3; ++i) {
        Layer& L = A.L[i];
        L.pred = (const float*)d_in[8 * i + 0];
        L.b    = (const int*)  d_in[8 * i + 1];
        L.a    = (const int*)  d_in[8 * i + 2];
        L.gj   = (const int*)  d_in[8 * i + 3];
        L.gi   = (const int*)  d_in[8 * i + 4];
        L.tbox = (const float*)d_in[8 * i + 5];
        L.tcls = (const int*)  d_in[8 * i + 6];
        L.anc  = (const float*)d_in[8 * i + 7];
        L.winner = (unsigned int*)(ws + winner_off[i]);
        L.iou    = (float*)(ws + iou_off[i]);
        L.g = g[i];
        L.n = n[i];
    }
    float* acc = (float*)ws;

    // zero accumulators + winner arrays (d_ws is poisoned before every call)
    hipMemsetAsync(d_ws, 0, zero_bytes, stream);

    // entry kernel
    {
        int b0 = (n[0] + 255) / 256, b1 = (n[1] + 255) / 256, b2 = (n[2] + 255) / 256;
        A.cum0 = b0; A.cum1 = b0 + b1;
        entry_kernel<<<b0 + b1 + b2, 256, 0, stream>>>(A, acc);
    }
    // cls kernel
    {
        int b0 = (n[0] * NC + 255) / 256, b1 = (n[1] * NC + 255) / 256, b2 = (n[2] * NC + 255) / 256;
        A.cum0 = b0; A.cum1 = b0 + b1;
        cls_kernel<<<b0 + b1 + b2, 256, 0, stream>>>(A, acc);
    }
    // obj kernel (must run after entry_kernel: reads winner/iou)
    {
        int b0 = (cells[0] + 255) / 256, b1 = (cells[1] + 255) / 256, b2 = (cells[2] + 255) / 256;
        A.cum0 = b0; A.cum1 = b0 + b1;
        obj_kernel<<<b0 + b1 + b2, 256, 0, stream>>>(A, acc);
    }
    final_kernel<<<1, 1, 0, stream>>>(acc, (float*)d_out,
                                      n[0], n[1], n[2],
                                      cells[0], cells[1], cells[2]);
}